// Round 7
// baseline (255.031 us; speedup 1.0000x reference)
//
#include <hip/hip_runtime.h>

#define EPS_ 1e-6f

typedef __attribute__((ext_vector_type(8))) short bf16x8;
typedef __attribute__((ext_vector_type(4))) float f32x4;

__device__ __forceinline__ unsigned short f2b(float f){
  union { float f; unsigned int u; } v; v.f = f;
  unsigned int r = v.u + 0x7fffu + ((v.u >> 16) & 1u);
  return (unsigned short)(r >> 16);
}
__device__ __forceinline__ unsigned int packrne(float a, float b){
  return (unsigned int)f2b(a) | ((unsigned int)f2b(b) << 16);
}
__device__ __forceinline__ unsigned int packtr(float a, float b){
  return (__float_as_uint(a) >> 16) | (__float_as_uint(b) & 0xffff0000u);
}
union cvt8 { unsigned int u[4]; bf16x8 v; };

// ---------- K0: weight bf16 conversion (blocks 0..255) + style LN + K/V
//              projection via MFMA (blocks 256..263) ----------
__global__ __launch_bounds__(256) void k_prep(
    const float* __restrict__ Wq, const float* __restrict__ Wk,
    const float* __restrict__ Wv, const float* __restrict__ Wo,
    const float* __restrict__ s, const float* __restrict__ lns_w,
    const float* __restrict__ lns_b,
    unsigned short* __restrict__ bWq, unsigned short* __restrict__ bWo,
    unsigned short* __restrict__ Kb, unsigned short* __restrict__ Vb){
  __shared__ unsigned short snb[64*264];
  int t = threadIdx.x;
  int blk = blockIdx.x;
  if (blk < 256){                           // Wq/Wo fp32 -> bf16, coalesced
    int i = blk*256 + t;
    bWq[i] = f2b(Wq[i]);
    bWo[i] = f2b(Wo[i]);
    return;
  }
  int idx = blk - 256;                      // 0..7
  int b = idx >> 2, n0 = (idx & 3) * 64;
  int tok = t >> 2, sub = t & 3;            // 4 lanes per token
  // ---- style LN (tokens n0..n0+64) ----
  {
    const float4* srow = (const float4*)(s + ((size_t)(b*256 + n0 + tok))*256 + sub*64);
    float4 vv[16];
    float s1 = 0.f, s2 = 0.f;
    #pragma unroll
    for (int j=0;j<16;++j){
      float4 v = srow[j]; vv[j] = v;
      s1 += (v.x+v.y)+(v.z+v.w);
      s2 += (v.x*v.x+v.y*v.y)+(v.z*v.z+v.w*v.w);
    }
    s1 += __shfl_xor(s1,1); s1 += __shfl_xor(s1,2);
    s2 += __shfl_xor(s2,1); s2 += __shfl_xor(s2,2);
    float mu = s1*(1.f/256.f);
    float rstd = rsqrtf(s2*(1.f/256.f) - mu*mu + EPS_);
    const float4* wr = (const float4*)(lns_w + sub*64);
    const float4* br = (const float4*)(lns_b + sub*64);
    #pragma unroll
    for (int j=0;j<16;++j){
      float4 v = vv[j], g = wr[j], o = br[j];
      float n0v = (v.x-mu)*rstd*g.x + o.x;
      float n1v = (v.y-mu)*rstd*g.y + o.y;
      float n2v = (v.z-mu)*rstd*g.z + o.z;
      float n3v = (v.w-mu)*rstd*g.w + o.w;
      uint2 pk = { packrne(n0v,n1v), packrne(n2v,n3v) };
      *(uint2*)&snb[tok*264 + sub*64 + j*4] = pk;
    }
  }
  __syncthreads();
  // ---- K and V projection: MFMA, weights converted on the fly ----
  int lane = t & 63, w = t >> 6, quad = lane >> 4, l16 = lane & 15;
  #pragma unroll
  for (int mat = 0; mat < 2; ++mat){
    const float* W = mat ? Wv : Wk;
    f32x4 acc[4][4];
    #pragma unroll
    for (int ot=0;ot<4;++ot)
      #pragma unroll
      for (int nt=0;nt<4;++nt) acc[ot][nt] = (f32x4){0.f,0.f,0.f,0.f};
    for (int ks=0; ks<8; ++ks){
      bf16x8 afr[4], bfr[4];
      #pragma unroll
      for (int ot=0;ot<4;++ot){
        const float4* wr = (const float4*)(W + (size_t)(w*64 + ot*16 + l16)*256 + ks*32 + quad*8);
        float4 a0 = wr[0], a1 = wr[1];
        cvt8 cv;
        cv.u[0]=packrne(a0.x,a0.y); cv.u[1]=packrne(a0.z,a0.w);
        cv.u[2]=packrne(a1.x,a1.y); cv.u[3]=packrne(a1.z,a1.w);
        afr[ot] = cv.v;
      }
      #pragma unroll
      for (int nt=0;nt<4;++nt)
        bfr[nt] = *(const bf16x8*)&snb[(nt*16+l16)*264 + ks*32 + quad*8];
      #pragma unroll
      for (int ot=0;ot<4;++ot)
        #pragma unroll
        for (int nt=0;nt<4;++nt)
          acc[ot][nt] = __builtin_amdgcn_mfma_f32_16x16x32_bf16(afr[ot], bfr[nt], acc[ot][nt], 0,0,0);
    }
    #pragma unroll
    for (int ot=0;ot<4;++ot){
      int otg = w*4 + ot;                   // 0..15
      int h = otg >> 1, dbase = (otg&1)*16 + quad*4;
      #pragma unroll
      for (int nt=0;nt<4;++nt){
        int n = n0 + nt*16 + l16;
        if (mat == 0){
          uint2 pk = { packrne(acc[ot][nt][0], acc[ot][nt][1]),
                       packrne(acc[ot][nt][2], acc[ot][nt][3]) };
          *(uint2*)&Kb[(((size_t)(b*8+h))*256 + n)*32 + dbase] = pk;
        } else {
          #pragma unroll
          for (int r=0;r<4;++r)
            Vb[(((size_t)(b*8+h))*32 + dbase + r)*256 + n] = f2b(acc[ot][nt][r]);
        }
      }
    }
    if (mat == 0) __syncthreads();          // keep snb stable (paranoia; reads done)
  }
}

// ---------- K1: fused LN + Qproj + attention (S^T form) + Wo + residual ----
// 1024 blocks x 32 positions, 4 waves. wave w: p-tile = w&1, head-half = w>>1.
__global__ __launch_bounds__(256,3) void k_mega(
    const float* __restrict__ x, const float* __restrict__ ln_w,
    const float* __restrict__ ln_b,
    const unsigned short* __restrict__ bWq, const unsigned short* __restrict__ bWo,
    const unsigned short* __restrict__ Kb, const unsigned short* __restrict__ Vb,
    const float* __restrict__ bo, float* __restrict__ out){
  __shared__ unsigned short buf1[32*264];   // hn -> q -> bf16 partial combine
  __shared__ unsigned short Pt[4][16*136];  // per-wave P^T [p][n]
  __shared__ float st[512];
  int t = threadIdx.x;
  int blk = blockIdx.x;                     // 0..1023
  int b = blk >> 9, p0 = (blk & 511) << 5;
  int pp = t & 31, seg = t >> 5;            // 8 segs x 32 channels
  const float* xb = x + ((size_t)b << 22) + p0 + pp;

  // ---- channel LN: single x pass, bf16 staged in buf1 ----
  float s1=0.f, s2=0.f;
  for (int k=0;k<16;++k){
    int c = seg*32 + 2*k;
    float v0 = xb[(size_t)c << 14], v1 = xb[(size_t)(c+1) << 14];
    s1 += v0+v1; s2 += v0*v0+v1*v1;
    *(unsigned int*)&buf1[pp*264 + c] = packrne(v0, v1);
  }
  st[seg*32+pp] = s1; st[256+seg*32+pp] = s2;
  __syncthreads();
  float a=0.f, q=0.f;
  #pragma unroll
  for (int g=0; g<8; ++g){ a += st[g*32+pp]; q += st[256+g*32+pp]; }
  float mu = a*(1.f/256.f);
  float rstd = rsqrtf(q*(1.f/256.f) - mu*mu + EPS_);
  for (int k=0;k<16;++k){
    int c = seg*32 + 2*k;
    unsigned int pk = *(unsigned int*)&buf1[pp*264 + c];
    float v0 = __uint_as_float(pk << 16);
    float v1 = __uint_as_float(pk & 0xffff0000u);
    v0 = (v0-mu)*rstd*ln_w[c]   + ln_b[c];
    v1 = (v1-mu)*rstd*ln_w[c+1] + ln_b[c+1];
    *(unsigned int*)&buf1[pp*264 + c] = packrne(v0, v1);
  }
  __syncthreads();

  int lane = t & 63, w = t >> 6, quad = lane >> 4, l16 = lane & 15;
  int ptile = w & 1, ohalf = w >> 1;
  int prow = ptile*16 + l16;                // local position row in buf1

  // ---- Q-proj: wave w -> o in [ohalf*128, +128) for its 16 positions ----
  {
    f32x4 acc[8];
    #pragma unroll
    for (int ot=0;ot<8;++ot) acc[ot] = (f32x4){0.f,0.f,0.f,0.f};
    const unsigned short* wq = bWq + (size_t)(ohalf*128 + l16)*256 + quad*8;
    for (int ks=0; ks<8; ++ks){
      bf16x8 bfr = *(const bf16x8*)&buf1[prow*264 + ks*32 + quad*8];
      #pragma unroll
      for (int ot=0;ot<8;++ot){
        bf16x8 afr = *(const bf16x8*)(wq + (size_t)ot*16*256 + ks*32);
        acc[ot] = __builtin_amdgcn_mfma_f32_16x16x32_bf16(afr, bfr, acc[ot], 0,0,0);
      }
    }
    __syncthreads();                        // hn reads complete before overwrite
    #pragma unroll
    for (int ot=0;ot<8;++ot){
      uint2 pk = { packrne(acc[ot][0], acc[ot][1]), packrne(acc[ot][2], acc[ot][3]) };
      *(uint2*)&buf1[prow*264 + ohalf*128 + ot*16 + quad*4] = pk;
    }
  }
  __syncthreads();                          // q ready

  // ---- heads loop (barrier-free): wave handles heads ohalf*4..+4 ----
  f32x4 oacc[16];
  #pragma unroll
  for (int ot=0;ot<16;++ot) oacc[ot] = (f32x4){0.f,0.f,0.f,0.f};
  const float c1 = 0.17677669529663689f * 1.44269504088896341f; // scale*log2e
  unsigned short* Pw = Pt[w];
  for (int hh=0; hh<4; ++hh){
    int h = ohalf*4 + hh;
    int bh = b*8 + h;
    // S^T[n][p] = K[n][:]·q[p][:]  (A=K, B=q)
    bf16x8 qf = *(const bf16x8*)&buf1[prow*264 + h*32 + quad*8];
    const unsigned short* kb = Kb + (size_t)bh*8192 + quad*8;
    f32x4 sc[16];
    #pragma unroll
    for (int nt=0;nt<16;++nt){
      bf16x8 kf = *(const bf16x8*)(kb + (size_t)(nt*16+l16)*32);
      f32x4 z = {0.f,0.f,0.f,0.f};
      sc[nt] = __builtin_amdgcn_mfma_f32_16x16x32_bf16(kf, qf, z, 0,0,0);
    }
    // softmax over n (col p = l16): in-lane 64 values + 2 shfl
    float mx = -1e30f;
    #pragma unroll
    for (int nt=0;nt<16;++nt)
      #pragma unroll
      for (int r=0;r<4;++r) mx = fmaxf(mx, sc[nt][r]);
    mx = fmaxf(mx, __shfl_xor(mx, 16));
    mx = fmaxf(mx, __shfl_xor(mx, 32));
    float mc = mx*c1, sm = 0.f;
    #pragma unroll
    for (int nt=0;nt<16;++nt)
      #pragma unroll
      for (int r=0;r<4;++r){
        float e = exp2f(fmaf(sc[nt][r], c1, -mc));
        sc[nt][r] = e; sm += e;
      }
    sm += __shfl_xor(sm, 16);
    sm += __shfl_xor(sm, 32);
    // P^T (unnormalized, trunc-packed) -> Pt [p][n]: 16 uint2 stores
    #pragma unroll
    for (int nt=0;nt<16;++nt){
      uint2 pk = { packtr(sc[nt][0], sc[nt][1]), packtr(sc[nt][2], sc[nt][3]) };
      *(uint2*)&Pw[l16*136 + nt*16 + quad*4] = pk;
    }
    // PV^T: av[d][p] = V^T[d][:]·P^T[:][p]  (A=V^T from Vb[d][n], B=P^T)
    f32x4 av[2] = {{0.f,0.f,0.f,0.f},{0.f,0.f,0.f,0.f}};
    const unsigned short* vb = Vb + (size_t)bh*8192 + quad*8;
    for (int ks=0; ks<8; ++ks){
      bf16x8 pf = *(const bf16x8*)&Pw[l16*136 + ks*32 + quad*8];
      #pragma unroll
      for (int dt=0; dt<2; ++dt){
        bf16x8 vf = *(const bf16x8*)(vb + (size_t)(dt*16+l16)*256 + ks*32);
        av[dt] = __builtin_amdgcn_mfma_f32_16x16x32_bf16(vf, pf, av[dt], 0,0,0);
      }
    }
    // deferred softmax denominator + regroup av (D-layout) -> Wo B-frag
    float inv = 1.f/sm;
    unsigned int pl0 = packrne(av[0][0]*inv, av[0][1]*inv);
    unsigned int ph0 = packrne(av[0][2]*inv, av[0][3]*inv);
    unsigned int pl1 = packrne(av[1][0]*inv, av[1][1]*inv);
    unsigned int ph1 = packrne(av[1][2]*inv, av[1][3]*inv);
    int s0 = ((quad & 1) << 5) + l16;       // src lane: quad (quad&1)*2
    int s1_ = s0 + 16;                      // src lane: quad (quad&1)*2+1
    unsigned int a0 = (unsigned int)__shfl((int)pl0, s0);
    unsigned int a1 = (unsigned int)__shfl((int)ph0, s0);
    unsigned int a2 = (unsigned int)__shfl((int)pl0, s1_);
    unsigned int a3 = (unsigned int)__shfl((int)ph0, s1_);
    unsigned int b0 = (unsigned int)__shfl((int)pl1, s0);
    unsigned int b1 = (unsigned int)__shfl((int)ph1, s0);
    unsigned int b2 = (unsigned int)__shfl((int)pl1, s1_);
    unsigned int b3 = (unsigned int)__shfl((int)ph1, s1_);
    bool hi = quad >= 2;
    cvt8 cv;
    cv.u[0] = hi ? b0 : a0; cv.u[1] = hi ? b1 : a1;
    cv.u[2] = hi ? b2 : a2; cv.u[3] = hi ? b3 : a3;
    bf16x8 bfr = cv.v;
    // Wo partial: all 256 o for this wave's 16 positions, K=32 (head h)
    const unsigned short* wo = bWo + (size_t)l16*256 + h*32 + quad*8;
    #pragma unroll
    for (int ot=0;ot<16;++ot){
      bf16x8 afr = *(const bf16x8*)(wo + (size_t)ot*16*256);
      oacc[ot] = __builtin_amdgcn_mfma_f32_16x16x32_bf16(afr, bfr, oacc[ot], 0,0,0);
    }
  }

  // ---- combine head-halves through buf1 (bf16), then epilogue ----
  __syncthreads();                          // q dead; all heads done
  if (ohalf == 1){
    #pragma unroll
    for (int ot=0;ot<16;++ot){
      uint2 pk = { packrne(oacc[ot][0], oacc[ot][1]), packrne(oacc[ot][2], oacc[ot][3]) };
      *(uint2*)&buf1[prow*264 + ot*16 + quad*4] = pk;
    }
  }
  __syncthreads();
  if (ohalf == 0){
    int p = p0 + ptile*16 + l16;
    const float* xr = x + ((size_t)b << 22) + p;
    float* op = out + ((size_t)b << 22) + p;
    #pragma unroll
    for (int ot=0;ot<16;++ot){
      unsigned int pk0 = *(unsigned int*)&buf1[prow*264 + ot*16 + quad*4];
      unsigned int pk1 = *(unsigned int*)&buf1[prow*264 + ot*16 + quad*4 + 2];
      float e0 = __uint_as_float(pk0 << 16);
      float e1 = __uint_as_float(pk0 & 0xffff0000u);
      float e2 = __uint_as_float(pk1 << 16);
      float e3 = __uint_as_float(pk1 & 0xffff0000u);
      int o = ot*16 + quad*4;
      float4 bov = *(const float4*)(bo + o);
      op[(size_t)(o  ) << 14] = oacc[ot][0] + e0 + bov.x + xr[(size_t)(o  ) << 14];
      op[(size_t)(o+1) << 14] = oacc[ot][1] + e1 + bov.y + xr[(size_t)(o+1) << 14];
      op[(size_t)(o+2) << 14] = oacc[ot][2] + e2 + bov.z + xr[(size_t)(o+2) << 14];
      op[(size_t)(o+3) << 14] = oacc[ot][3] + e3 + bov.w + xr[(size_t)(o+3) << 14];
    }
  }
}

extern "C" void kernel_launch(void* const* d_in, const int* in_sizes, int n_in,
                              void* d_out, int out_size, void* d_ws, size_t ws_size,
                              hipStream_t stream) {
  const float* x     = (const float*)d_in[0];
  const float* s     = (const float*)d_in[1];
  const float* ln_w  = (const float*)d_in[2];
  const float* ln_b  = (const float*)d_in[3];
  const float* lns_w = (const float*)d_in[4];
  const float* lns_b = (const float*)d_in[5];
  const float* Wq    = (const float*)d_in[6];
  const float* Wk    = (const float*)d_in[7];
  const float* Wv    = (const float*)d_in[8];
  const float* Wo    = (const float*)d_in[9];
  const float* bo    = (const float*)d_in[10];
  float* out = (float*)d_out;

  unsigned short* bWq = (unsigned short*)d_ws;  //  65536 us
  unsigned short* bWo = bWq + 65536;            //  65536 us
  unsigned short* Kb  = bWo + 65536;            // 131072 us  [bh][n][d]
  unsigned short* Vb  = Kb + 131072;            // 131072 us  [bh][d][n]
  // total ws: 786 KB

  k_prep<<<264,  256, 0, stream>>>(Wq, Wk, Wv, Wo, s, lns_w, lns_b, bWq, bWo, Kb, Vb);
  k_mega<<<1024, 256, 0, stream>>>(x, ln_w, ln_b, bWq, bWo, Kb, Vb, bo, out);
}

// Round 8
// 212.602 us; speedup vs baseline: 1.1996x; 1.1996x over previous
//
#include <hip/hip_runtime.h>

#define EPS_ 1e-6f

typedef __attribute__((ext_vector_type(8))) short bf16x8;
typedef __attribute__((ext_vector_type(4))) float f32x4;

__device__ __forceinline__ unsigned short f2b(float f){
  union { float f; unsigned int u; } v; v.f = f;
  unsigned int r = v.u + 0x7fffu + ((v.u >> 16) & 1u);
  return (unsigned short)(r >> 16);
}
__device__ __forceinline__ unsigned int packrne(float a, float b){
  return (unsigned int)f2b(a) | ((unsigned int)f2b(b) << 16);
}
__device__ __forceinline__ unsigned int packtr(float a, float b){
  return (__float_as_uint(a) >> 16) | (__float_as_uint(b) & 0xffff0000u);
}
union cvt8 { unsigned int u[4]; bf16x8 v; };

// ---------- K0: weight bf16 conversion (blocks 0..255) + style LN + K/V
//              projection via MFMA (blocks 256..263) ----------
__global__ __launch_bounds__(256) void k_prep(
    const float* __restrict__ Wq, const float* __restrict__ Wk,
    const float* __restrict__ Wv, const float* __restrict__ Wo,
    const float* __restrict__ s, const float* __restrict__ lns_w,
    const float* __restrict__ lns_b,
    unsigned short* __restrict__ bWq, unsigned short* __restrict__ bWo,
    unsigned short* __restrict__ Kb, unsigned short* __restrict__ Vb){
  __shared__ unsigned short snb[64*264];
  int t = threadIdx.x;
  int blk = blockIdx.x;
  if (blk < 256){                           // Wq/Wo fp32 -> bf16, coalesced
    int i = blk*256 + t;
    bWq[i] = f2b(Wq[i]);
    bWo[i] = f2b(Wo[i]);
    return;
  }
  int idx = blk - 256;                      // 0..7
  int b = idx >> 2, n0 = (idx & 3) * 64;
  int tok = t >> 2, sub = t & 3;            // 4 lanes per token
  {
    const float4* srow = (const float4*)(s + ((size_t)(b*256 + n0 + tok))*256 + sub*64);
    float4 vv[16];
    float s1 = 0.f, s2 = 0.f;
    #pragma unroll
    for (int j=0;j<16;++j){
      float4 v = srow[j]; vv[j] = v;
      s1 += (v.x+v.y)+(v.z+v.w);
      s2 += (v.x*v.x+v.y*v.y)+(v.z*v.z+v.w*v.w);
    }
    s1 += __shfl_xor(s1,1); s1 += __shfl_xor(s1,2);
    s2 += __shfl_xor(s2,1); s2 += __shfl_xor(s2,2);
    float mu = s1*(1.f/256.f);
    float rstd = rsqrtf(s2*(1.f/256.f) - mu*mu + EPS_);
    const float4* wr = (const float4*)(lns_w + sub*64);
    const float4* br = (const float4*)(lns_b + sub*64);
    #pragma unroll
    for (int j=0;j<16;++j){
      float4 v = vv[j], g = wr[j], o = br[j];
      float n0v = (v.x-mu)*rstd*g.x + o.x;
      float n1v = (v.y-mu)*rstd*g.y + o.y;
      float n2v = (v.z-mu)*rstd*g.z + o.z;
      float n3v = (v.w-mu)*rstd*g.w + o.w;
      uint2 pk = { packrne(n0v,n1v), packrne(n2v,n3v) };
      *(uint2*)&snb[tok*264 + sub*64 + j*4] = pk;
    }
  }
  __syncthreads();
  int lane = t & 63, w = t >> 6, quad = lane >> 4, l16 = lane & 15;
  #pragma unroll
  for (int mat = 0; mat < 2; ++mat){
    const float* W = mat ? Wv : Wk;
    f32x4 acc[4][4];
    #pragma unroll
    for (int ot=0;ot<4;++ot)
      #pragma unroll
      for (int nt=0;nt<4;++nt) acc[ot][nt] = (f32x4){0.f,0.f,0.f,0.f};
    for (int ks=0; ks<8; ++ks){
      bf16x8 afr[4], bfr[4];
      #pragma unroll
      for (int ot=0;ot<4;++ot){
        const float4* wr = (const float4*)(W + (size_t)(w*64 + ot*16 + l16)*256 + ks*32 + quad*8);
        float4 a0 = wr[0], a1 = wr[1];
        cvt8 cv;
        cv.u[0]=packrne(a0.x,a0.y); cv.u[1]=packrne(a0.z,a0.w);
        cv.u[2]=packrne(a1.x,a1.y); cv.u[3]=packrne(a1.z,a1.w);
        afr[ot] = cv.v;
      }
      #pragma unroll
      for (int nt=0;nt<4;++nt)
        bfr[nt] = *(const bf16x8*)&snb[(nt*16+l16)*264 + ks*32 + quad*8];
      #pragma unroll
      for (int ot=0;ot<4;++ot)
        #pragma unroll
        for (int nt=0;nt<4;++nt)
          acc[ot][nt] = __builtin_amdgcn_mfma_f32_16x16x32_bf16(afr[ot], bfr[nt], acc[ot][nt], 0,0,0);
    }
    #pragma unroll
    for (int ot=0;ot<4;++ot){
      int otg = w*4 + ot;                   // 0..15
      int h = otg >> 1, dbase = (otg&1)*16 + quad*4;
      #pragma unroll
      for (int nt=0;nt<4;++nt){
        int n = n0 + nt*16 + l16;
        if (mat == 0){
          uint2 pk = { packrne(acc[ot][nt][0], acc[ot][nt][1]),
                       packrne(acc[ot][nt][2], acc[ot][nt][3]) };
          *(uint2*)&Kb[(((size_t)(b*8+h))*256 + n)*32 + dbase] = pk;
        } else {
          #pragma unroll
          for (int r=0;r<4;++r)
            Vb[(((size_t)(b*8+h))*32 + dbase + r)*256 + n] = f2b(acc[ot][nt][r]);
        }
      }
    }
    if (mat == 0) __syncthreads();
  }
}

// ---------- K1: fused LN + Qproj + attention + Wo + residual ----------
// 1024 blocks x 32 positions, 4 waves. wave = (ptile = w&1, ohalf = w>>1).
// Heads loop is barrier-free; P never touches LDS (shfl transform).
__global__ __launch_bounds__(256,4) void k_mega(
    const float* __restrict__ x, const float* __restrict__ ln_w,
    const float* __restrict__ ln_b,
    const unsigned short* __restrict__ bWq, const unsigned short* __restrict__ bWo,
    const unsigned short* __restrict__ Kb, const unsigned short* __restrict__ Vb,
    const float* __restrict__ bo, float* __restrict__ out){
  __shared__ unsigned short buf1[32*264];   // hn -> q -> att   (16896 B)
  __shared__ float st[512];                 //                  ( 2048 B)
  int t = threadIdx.x;
  int blk = blockIdx.x;                     // 0..1023
  int b = blk >> 9, p0 = (blk & 511) << 5;
  int pp = t & 31, seg = t >> 5;            // 8 segs x 32 channels
  const float* xb = x + ((size_t)b << 22) + p0 + pp;

  // ---- channel LN: single x pass, bf16 staged in buf1 [p][c] ----
  float s1=0.f, s2=0.f;
  for (int k=0;k<16;++k){
    int c = seg*32 + 2*k;
    float v0 = xb[(size_t)c << 14], v1 = xb[(size_t)(c+1) << 14];
    s1 += v0+v1; s2 += v0*v0+v1*v1;
    *(unsigned int*)&buf1[pp*264 + c] = packrne(v0, v1);
  }
  st[seg*32+pp] = s1; st[256+seg*32+pp] = s2;
  __syncthreads();
  float a=0.f, q=0.f;
  #pragma unroll
  for (int g=0; g<8; ++g){ a += st[g*32+pp]; q += st[256+g*32+pp]; }
  float mu = a*(1.f/256.f);
  float rstd = rsqrtf(q*(1.f/256.f) - mu*mu + EPS_);
  for (int k=0;k<16;++k){
    int c = seg*32 + 2*k;
    unsigned int pk = *(unsigned int*)&buf1[pp*264 + c];
    float v0 = __uint_as_float(pk << 16);
    float v1 = __uint_as_float(pk & 0xffff0000u);
    v0 = (v0-mu)*rstd*ln_w[c]   + ln_b[c];
    v1 = (v1-mu)*rstd*ln_w[c+1] + ln_b[c+1];
    *(unsigned int*)&buf1[pp*264 + c] = packrne(v0, v1);
  }
  __syncthreads();

  int lane = t & 63, w = t >> 6, quad = lane >> 4, l16 = lane & 15;
  int ptile = w & 1, ohalf = w >> 1;
  int prow = ptile*16 + l16;

  // ---- Q-proj: wave w -> o range [w*64, +64), both p-tiles ----
  {
    f32x4 acc[4][2];
    #pragma unroll
    for (int ot=0;ot<4;++ot)
      #pragma unroll
      for (int pt=0;pt<2;++pt) acc[ot][pt] = (f32x4){0.f,0.f,0.f,0.f};
    const unsigned short* wq = bWq + (size_t)(w*64 + l16)*256 + quad*8;
    for (int ks=0; ks<8; ++ks){
      bf16x8 bfr[2], afr[4];
      #pragma unroll
      for (int pt=0;pt<2;++pt)
        bfr[pt] = *(const bf16x8*)&buf1[(pt*16+l16)*264 + ks*32 + quad*8];
      #pragma unroll
      for (int ot=0;ot<4;++ot)
        afr[ot] = *(const bf16x8*)(wq + (size_t)ot*16*256 + ks*32);
      #pragma unroll
      for (int ot=0;ot<4;++ot)
        #pragma unroll
        for (int pt=0;pt<2;++pt)
          acc[ot][pt] = __builtin_amdgcn_mfma_f32_16x16x32_bf16(afr[ot], bfr[pt], acc[ot][pt], 0,0,0);
    }
    __syncthreads();                        // all hn reads complete
    #pragma unroll
    for (int ot=0;ot<4;++ot){
      int o = w*64 + ot*16 + quad*4;
      #pragma unroll
      for (int pt=0;pt<2;++pt){
        uint2 pk = { packrne(acc[ot][pt][0], acc[ot][pt][1]),
                     packrne(acc[ot][pt][2], acc[ot][pt][3]) };
        *(uint2*)&buf1[(pt*16+l16)*264 + o] = pk;
      }
    }
  }
  __syncthreads();                          // q ready in buf1 [p][o]

  // ---- heads loop (barrier-free): wave handles heads ohalf*4..+4,
  //      positions ptile*16..+16. av overwrites q's head-slice in buf1. ----
  const float c1 = 0.17677669529663689f * 1.44269504088896341f; // scale*log2e
  int srcA = ((( 2*quad   )&3)<<4) + l16;
  int srcB = (((2*quad + 1)&3)<<4) + l16;
  bool hiq = quad >= 2;
  for (int hh=0; hh<4; ++hh){
    int h = ohalf*4 + hh;
    int bh = b*8 + h;
    // S^T[n][p]: A = K[n][d], B = q[p][d]
    bf16x8 qf = *(const bf16x8*)&buf1[prow*264 + h*32 + quad*8];
    const unsigned short* kb = Kb + (size_t)bh*8192 + quad*8;
    f32x4 sc[16];
    #pragma unroll
    for (int nt=0;nt<16;++nt){
      bf16x8 kf = *(const bf16x8*)(kb + (size_t)(nt*16+l16)*32);
      f32x4 z = {0.f,0.f,0.f,0.f};
      sc[nt] = __builtin_amdgcn_mfma_f32_16x16x32_bf16(kf, qf, z, 0,0,0);
    }
    // softmax over n for col p=l16: in-lane + 2 shfl
    float mx = -1e30f;
    #pragma unroll
    for (int nt=0;nt<16;++nt)
      #pragma unroll
      for (int r=0;r<4;++r) mx = fmaxf(mx, sc[nt][r]);
    mx = fmaxf(mx, __shfl_xor(mx, 16));
    mx = fmaxf(mx, __shfl_xor(mx, 32));
    float mc = mx*c1;
    float sm0=0.f, sm1=0.f, sm2=0.f, sm3=0.f;
    #pragma unroll
    for (int nt=0;nt<16;++nt){
      float e0 = exp2f(fmaf(sc[nt][0], c1, -mc));
      float e1 = exp2f(fmaf(sc[nt][1], c1, -mc));
      float e2 = exp2f(fmaf(sc[nt][2], c1, -mc));
      float e3 = exp2f(fmaf(sc[nt][3], c1, -mc));
      sc[nt][0]=e0; sc[nt][1]=e1; sc[nt][2]=e2; sc[nt][3]=e3;
      sm0+=e0; sm1+=e1; sm2+=e2; sm3+=e3;
    }
    float sm = (sm0+sm1)+(sm2+sm3);
    sm += __shfl_xor(sm, 16);
    sm += __shfl_xor(sm, 32);
    // pack P (trunc; P in (0,1])
    unsigned int pk[16][2];
    #pragma unroll
    for (int nt=0;nt<16;++nt){
      pk[nt][0] = packtr(sc[nt][0], sc[nt][1]);
      pk[nt][1] = packtr(sc[nt][2], sc[nt][3]);
    }
    // PV^T: A = V^T[d][n], B = P^T[n][p] built via shfl from pk
    f32x4 av[2] = {{0.f,0.f,0.f,0.f},{0.f,0.f,0.f,0.f}};
    const unsigned short* vb = Vb + (size_t)bh*8192 + quad*8;
    #pragma unroll
    for (int ks=0; ks<8; ++ks){
      unsigned int aA0 = (unsigned int)__shfl((int)pk[2*ks  ][0], srcA);
      unsigned int aB0 = (unsigned int)__shfl((int)pk[2*ks+1][0], srcA);
      unsigned int aA1 = (unsigned int)__shfl((int)pk[2*ks  ][1], srcA);
      unsigned int aB1 = (unsigned int)__shfl((int)pk[2*ks+1][1], srcA);
      unsigned int bA0 = (unsigned int)__shfl((int)pk[2*ks  ][0], srcB);
      unsigned int bB0 = (unsigned int)__shfl((int)pk[2*ks+1][0], srcB);
      unsigned int bA1 = (unsigned int)__shfl((int)pk[2*ks  ][1], srcB);
      unsigned int bB1 = (unsigned int)__shfl((int)pk[2*ks+1][1], srcB);
      cvt8 cv;
      cv.u[0] = hiq ? aB0 : aA0;
      cv.u[1] = hiq ? aB1 : aA1;
      cv.u[2] = hiq ? bB0 : bA0;
      cv.u[3] = hiq ? bB1 : bA1;
      bf16x8 pf = cv.v;
      #pragma unroll
      for (int dt=0; dt<2; ++dt){
        bf16x8 vf = *(const bf16x8*)(vb + (size_t)(dt*16+l16)*256 + ks*32);
        av[dt] = __builtin_amdgcn_mfma_f32_16x16x32_bf16(vf, pf, av[dt], 0,0,0);
      }
    }
    // normalize (deferred denominator) and write att into buf1 head-slice
    float inv = 1.f/sm;
    #pragma unroll
    for (int dt=0; dt<2; ++dt){
      uint2 pko = { packrne(av[dt][0]*inv, av[dt][1]*inv),
                    packrne(av[dt][2]*inv, av[dt][3]*inv) };
      *(uint2*)&buf1[prow*264 + h*32 + dt*16 + quad*4] = pko;
    }
  }
  __syncthreads();                          // att[32][256] complete in buf1

  // ---- Wo GEMM (K=256 from buf1) + bias + residual ----
  {
    f32x4 oacc[4][2];
    #pragma unroll
    for (int ot=0;ot<4;++ot)
      #pragma unroll
      for (int pt=0;pt<2;++pt) oacc[ot][pt] = (f32x4){0.f,0.f,0.f,0.f};
    const unsigned short* wo = bWo + (size_t)(w*64 + l16)*256 + quad*8;
    for (int ks=0; ks<8; ++ks){
      bf16x8 bfr[2], afr[4];
      #pragma unroll
      for (int pt=0;pt<2;++pt)
        bfr[pt] = *(const bf16x8*)&buf1[(pt*16+l16)*264 + ks*32 + quad*8];
      #pragma unroll
      for (int ot=0;ot<4;++ot)
        afr[ot] = *(const bf16x8*)(wo + (size_t)ot*16*256 + ks*32);
      #pragma unroll
      for (int ot=0;ot<4;++ot)
        #pragma unroll
        for (int pt=0;pt<2;++pt)
          oacc[ot][pt] = __builtin_amdgcn_mfma_f32_16x16x32_bf16(afr[ot], bfr[pt], oacc[ot][pt], 0,0,0);
    }
    #pragma unroll
    for (int ot=0;ot<4;++ot){
      int o = w*64 + ot*16 + quad*4;
      #pragma unroll
      for (int pt=0;pt<2;++pt){
        int p = p0 + pt*16 + l16;
        #pragma unroll
        for (int r=0;r<4;++r){
          size_t idx = (((size_t)b*256 + o + r) << 14) + p;
          out[idx] = oacc[ot][pt][r] + bo[o+r] + x[idx];
        }
      }
    }
  }
}

extern "C" void kernel_launch(void* const* d_in, const int* in_sizes, int n_in,
                              void* d_out, int out_size, void* d_ws, size_t ws_size,
                              hipStream_t stream) {
  const float* x     = (const float*)d_in[0];
  const float* s     = (const float*)d_in[1];
  const float* ln_w  = (const float*)d_in[2];
  const float* ln_b  = (const float*)d_in[3];
  const float* lns_w = (const float*)d_in[4];
  const float* lns_b = (const float*)d_in[5];
  const float* Wq    = (const float*)d_in[6];
  const float* Wk    = (const float*)d_in[7];
  const float* Wv    = (const float*)d_in[8];
  const float* Wo    = (const float*)d_in[9];
  const float* bo    = (const float*)d_in[10];
  float* out = (float*)d_out;

  unsigned short* bWq = (unsigned short*)d_ws;  //  65536 us
  unsigned short* bWo = bWq + 65536;            //  65536 us
  unsigned short* Kb  = bWo + 65536;            // 131072 us  [bh][n][d]
  unsigned short* Vb  = Kb + 131072;            // 131072 us  [bh][d][n]
  // total ws: 786 KB

  k_prep<<<264,  256, 0, stream>>>(Wq, Wk, Wv, Wo, s, lns_w, lns_b, bWq, bWo, Kb, Vb);
  k_mega<<<1024, 256, 0, stream>>>(x, ln_w, ln_b, bWq, bWo, Kb, Vb, bo, out);
}